// Round 7
// baseline (543.230 us; speedup 1.0000x reference)
//
#include <hip/hip_runtime.h>
#include <math.h>

// GraphConvolution (GCNII variant=True, residual=True), N=100k, E=1M, D=64.
//   agg[dst] += h[src] * edge_w
//   out = theta*([agg,i]@W) + (1-theta)*((1-alpha)*agg + alpha*i) + i
//
// R7: 3 dispatches total.
//   bin_fill: cvt h->bf16 + pack W->bf16 frags + bin edges into 128-node
//             buckets (782 logical bins, CAP 2048).
//   spmm_epi: one block per bin; direct LDS-atomic SpMM into a 128x68 fp32
//             accumulator (no sort, bucket read ONCE), then fused MFMA
//             epilogue from LDS -> out. agg never touches global memory.

#define DFEAT 64
#define BINSZ 128        // nodes per bin
#define NBINS 1024       // physical; logical = ceil(N/128) = 782
#define CAP   2048       // slots per bucket (mean 1280, sigma ~36 -> +21sigma)
#define CHUNK 4096       // edges per bin_fill block
#define TPB   512
#define APAD  68         // agg row stride (floats): 64 + 4 (16B-aligned pad)

typedef unsigned long long u64;
typedef __attribute__((ext_vector_type(8))) short bf16x8;
typedef __attribute__((ext_vector_type(4))) float f32x4;

__device__ inline unsigned short to_bf16(float f) {   // RNE
    unsigned u = __float_as_uint(f);
    u += 0x7FFF + ((u >> 16) & 1);
    return (unsigned short)(u >> 16);
}
__device__ inline float bf_up(unsigned short s) {
    return __uint_as_float(((unsigned)s) << 16);
}

// ---- phase 1: cvt h + pack W + bin edges by dst>>7 into global buckets ----
// Entry: low32 = src | (dstLocal<<24) (dl < 128), high32 = bits(w).
__global__ __launch_bounds__(512) void bin_fill_kernel(
    const float* __restrict__ h, const float* __restrict__ weight,
    const int* __restrict__ e_src, const int* __restrict__ e_dst,
    const float* __restrict__ e_w, int* __restrict__ gcur,
    u64* __restrict__ bucket, ushort* __restrict__ h16,
    ushort* __restrict__ w16, int E, int total4) {
    __shared__ u64 staging[CHUNK];            // 32 KB
    __shared__ unsigned short binOf[CHUNK];   // 8 KB
    __shared__ int hist[NBINS], offs[NBINS], gbase[NBINS], cur[NBINS]; // 16 KB
    __shared__ int part[TPB];                 // 2 KB

    int tid = threadIdx.x;
    int gid = blockIdx.x * TPB + tid;
    int nthreads = gridDim.x * TPB;

    // 0a: h (fp32) -> h16 (bf16), grid-stride over ushort4 groups
    for (int i = gid; i < total4; i += nthreads) {
        float4 v = ((const float4*)h)[i];
        ushort4 o;
        o.x = to_bf16(v.x); o.y = to_bf16(v.y);
        o.z = to_bf16(v.z); o.w = to_bf16(v.w);
        ((ushort4*)h16)[i] = o;
    }
    // 0b: W (128x64 fp32) -> frag-packed bf16: w16[((c*4+s)*64+l)*8+j]
    //     = bf16(W[s*32 + (l>>4)*8 + j][c*16 + (l&15)])
    if (gid < 8192) {
        int j = gid & 7, l = (gid >> 3) & 63, cs = gid >> 9;
        int c = cs >> 2, s = cs & 3, q = l >> 4, m = l & 15;
        w16[gid] = to_bf16(weight[(s * 32 + q * 8 + j) * DFEAT + c * 16 + m]);
    }

    int e0 = blockIdx.x * CHUNK;
    int cc = min(CHUNK, E - e0);

    hist[tid] = 0; hist[tid + 512] = 0;
    __syncthreads();

    int d[8], s[8];
    float w[8];
#pragma unroll
    for (int j = 0; j < 8; ++j) {
        int e = e0 + j * TPB + tid;
        if (e < E) { d[j] = e_dst[e]; s[j] = e_src[e]; w[j] = e_w[e]; }
        else d[j] = -1;
    }
#pragma unroll
    for (int j = 0; j < 8; ++j)
        if (d[j] >= 0) atomicAdd(&hist[d[j] >> 7], 1);
    __syncthreads();

    // exclusive scan of hist[1024]: thread t owns pair (2t, 2t+1)
    int a = hist[2 * tid], b = hist[2 * tid + 1];
    part[tid] = a + b;
    __syncthreads();
    for (int ofs = 1; ofs < TPB; ofs <<= 1) {
        int t = (tid >= ofs) ? part[tid - ofs] : 0;
        __syncthreads();
        part[tid] += t;
        __syncthreads();
    }
    int excl = part[tid] - (a + b);
    offs[2 * tid] = excl;         cur[2 * tid] = excl;
    offs[2 * tid + 1] = excl + a; cur[2 * tid + 1] = excl + a;
    __syncthreads();

    // scatter into bin-sorted LDS staging
#pragma unroll
    for (int j = 0; j < 8; ++j) {
        if (d[j] >= 0) {
            int bb = d[j] >> 7;
            int p = atomicAdd(&cur[bb], 1);
            unsigned lo = (unsigned)s[j] | ((unsigned)(d[j] & 127) << 24);
            staging[p] = ((u64)(unsigned)__float_as_int(w[j]) << 32) | lo;
            binOf[p] = (unsigned short)bb;
        }
    }
    __syncthreads();

    // reserve global space: one atomic per non-empty bin
    for (int t = tid; t < NBINS; t += TPB) {
        int c = hist[t];
        gbase[t] = (c > 0) ? atomicAdd(&gcur[t], c) : 0;
    }
    __syncthreads();

    // flush: bin-contiguous runs -> contiguous global slots
#pragma unroll
    for (int j = 0; j < 8; ++j) {
        int p = j * TPB + tid;
        if (p < cc) {
            int bb = binOf[p];
            bucket[(size_t)bb * CAP + gbase[bb] + (p - offs[bb])] = staging[p];
        }
    }
}

// ---- phase 2: fused SpMM (LDS-atomic accumulate) + MFMA epilogue ----
// One block per 128-node bin, 512 threads (8 waves), ~50 KB LDS -> 3 blk/CU.
// Accumulate: 32 lanes per edge, lane k covers features {2k, 2k+1}; 4-deep
// unroll -> 8 edges in flight per wave. Then each wave runs the MFMA
// epilogue for one 16-row tile (A-agg from LDS, A-i from global, B from LDS).
__global__ __launch_bounds__(512, 6) void spmm_epi_kernel(
    const ushort* __restrict__ h16, const u64* __restrict__ bucket,
    const int* __restrict__ gcur, const ushort* __restrict__ w16,
    const float* __restrict__ ifeat,
    const float* __restrict__ lamda_p, const float* __restrict__ alpha_p,
    const int* __restrict__ layer_p,
    float* __restrict__ out, int N) {
    __shared__ float agg[BINSZ * APAD];   // 34.8 KB
    __shared__ ushort sW[8192];           // 16 KB  (bf16 B-frags)

    int tid = threadIdx.x;
    int lane = tid & 63, wv = tid >> 6;
    int bin = blockIdx.x;
    int base = bin << 7;

    for (int i = tid; i < BINSZ * APAD; i += TPB) agg[i] = 0.f;
    for (int i = tid; i < 4096; i += TPB)
        ((unsigned*)sW)[i] = ((const unsigned*)w16)[i];
    int cnt = gcur[bin];
    __syncthreads();

    // accumulate
    {
        int half = lane >> 5;       // which edge of the pair
        int k = lane & 31;          // feature pair index
        const u64* bk = bucket + (size_t)bin * CAP;
        for (int e0 = wv * 8; e0 < cnt; e0 += 64) {
#pragma unroll
            for (int j = 0; j < 4; ++j) {
                int idx = e0 + 2 * j + half;
                u64 e = bk[min(idx, cnt - 1)];
                float wt = (idx < cnt) ? __int_as_float((int)(e >> 32)) : 0.f;
                int src = ((unsigned)e) & 0xFFFFFF;
                int dl = (((unsigned)e) >> 24) & 127;
                ushort2 hv = *(const ushort2*)(h16 + (size_t)src * DFEAT + 2 * k);
                atomicAdd(&agg[dl * APAD + 2 * k], wt * bf_up(hv.x));
                atomicAdd(&agg[dl * APAD + 2 * k + 1], wt * bf_up(hv.y));
            }
        }
    }
    __syncthreads();

    // fused epilogue: wave wv handles rows [wv*16, wv*16+16)
    float alf = alpha_p[0];
    float theta = fminf(1.0f, logf(lamda_p[0] / (float)layer_p[0] + 1.0f));
    int q = lane >> 4, m = lane & 15;
    int rL = wv * 16 + m;
    int rG = base + rL;

    f32x4 acc[4] = {{0.f, 0.f, 0.f, 0.f}, {0.f, 0.f, 0.f, 0.f},
                    {0.f, 0.f, 0.f, 0.f}, {0.f, 0.f, 0.f, 0.f}};

    // A slices from agg (LDS), s = 0,1
#pragma unroll
    for (int s = 0; s < 2; ++s) {
        const float* p = &agg[rL * APAD + s * 32 + q * 8];
        f32x4 v0 = *(const f32x4*)p;
        f32x4 v1 = *(const f32x4*)(p + 4);
        bf16x8 fa;
        fa[0] = (short)to_bf16(v0[0]); fa[1] = (short)to_bf16(v0[1]);
        fa[2] = (short)to_bf16(v0[2]); fa[3] = (short)to_bf16(v0[3]);
        fa[4] = (short)to_bf16(v1[0]); fa[5] = (short)to_bf16(v1[1]);
        fa[6] = (short)to_bf16(v1[2]); fa[7] = (short)to_bf16(v1[3]);
#pragma unroll
        for (int c = 0; c < 4; ++c) {
            bf16x8 bB = *(const bf16x8*)(sW + ((c * 4 + s) * 64 + lane) * 8);
            acc[c] = __builtin_amdgcn_mfma_f32_16x16x32_bf16(fa, bB, acc[c], 0, 0, 0);
        }
    }
    // A slices from i (global), s = 2,3
    {
        const float* ip = ifeat + (size_t)min(rG, N - 1) * DFEAT;
#pragma unroll
        for (int s = 0; s < 2; ++s) {
            float4 v0 = *(const float4*)(ip + s * 32 + q * 8);
            float4 v1 = *(const float4*)(ip + s * 32 + q * 8 + 4);
            bf16x8 fa;
            fa[0] = (short)to_bf16(v0.x); fa[1] = (short)to_bf16(v0.y);
            fa[2] = (short)to_bf16(v0.z); fa[3] = (short)to_bf16(v0.w);
            fa[4] = (short)to_bf16(v1.x); fa[5] = (short)to_bf16(v1.y);
            fa[6] = (short)to_bf16(v1.z); fa[7] = (short)to_bf16(v1.w);
#pragma unroll
            for (int c = 0; c < 4; ++c) {
                bf16x8 bB = *(const bf16x8*)(sW + ((c * 4 + s + 2) * 64 + lane) * 8);
                acc[c] = __builtin_amdgcn_mfma_f32_16x16x32_bf16(fa, bB, acc[c], 0, 0, 0);
            }
        }
    }

    // mix + residual + store (C/D: row = wv*16 + q*4 + r, col = c*16 + m)
#pragma unroll
    for (int c = 0; c < 4; ++c) {
        int col = c * 16 + m;
#pragma unroll
        for (int r = 0; r < 4; ++r) {
            int rowL = wv * 16 + q * 4 + r;
            int row = base + rowL;
            if (row < N) {
                float av = agg[rowL * APAD + col];
                float iv = ifeat[(size_t)row * DFEAT + col];
                out[(size_t)row * DFEAT + col] =
                    theta * acc[c][r] +
                    (1.f - theta) * ((1.f - alf) * av + alf * iv) + iv;
            }
        }
    }
}

extern "C" void kernel_launch(void* const* d_in, const int* in_sizes, int n_in,
                              void* d_out, int out_size, void* d_ws, size_t ws_size,
                              hipStream_t stream) {
    const float* h       = (const float*)d_in[0];
    const float* ifeat   = (const float*)d_in[1];
    const float* weight  = (const float*)d_in[2];
    const float* edge_w  = (const float*)d_in[3];
    const float* lamda_p = (const float*)d_in[4];
    const float* alpha_p = (const float*)d_in[5];
    const int*   e_src   = (const int*)d_in[6];
    const int*   e_dst   = (const int*)d_in[7];
    const int*   layer_p = (const int*)d_in[8];
    float* out = (float*)d_out;

    int N = in_sizes[0] / DFEAT;     // 100000
    int E = in_sizes[3];             // 1000000
    int nbins = (N + BINSZ - 1) >> 7;  // 782

    // ws: gcur[1024] (4KB) | bucket 1024*2048*8 = 16.78MB | h16 12.8MB | w16 16KB
    int* gcur = (int*)d_ws;
    u64* bucket = (u64*)((char*)d_ws + 4096);
    ushort* h16 = (ushort*)((char*)bucket + (size_t)NBINS * CAP * sizeof(u64));
    ushort* w16 = h16 + (size_t)N * DFEAT;

    hipMemsetAsync(gcur, 0, NBINS * sizeof(int), stream);

    int total4 = N * DFEAT / 4;
    bin_fill_kernel<<<(E + CHUNK - 1) / CHUNK, TPB, 0, stream>>>(
        h, weight, e_src, e_dst, edge_w, gcur, bucket, h16, w16, E, total4);

    spmm_epi_kernel<<<nbins, TPB, 0, stream>>>(
        h16, bucket, gcur, w16, ifeat, lamda_p, alpha_p, layer_p, out, N);
}

// Round 8
// 162.354 us; speedup vs baseline: 3.3460x; 3.3460x over previous
//
#include <hip/hip_runtime.h>
#include <math.h>

// GraphConvolution (GCNII variant=True, residual=True), N=100k, E=1M, D=64.
//   agg[dst] += h[src] * edge_w
//   out = theta*([agg,i]@W) + (1-theta)*((1-alpha)*agg + alpha*i) + i
//
// R8: 3 dispatches. LESSON (R3+R7, both ~440us): LDS f32 atomicAdd is
// catastrophically slow on gfx950 -- consumer must register-accumulate.
//   bin_fill: cvt h->bf16 + pack W->bf16 frags + bin edges into 128-node
//             bin-sorted buckets (R7-verified logic).
//   spmm:     per bin: counting-sort in LDS (int atomics = fine, R6-proven),
//             quad-parallel register-accumulate gather, agg->bf16 LDS tile,
//             fused MFMA epilogue -> out. agg never touches global.

#define DFEAT 64
#define BINSZ 128        // nodes per bin
#define NBINS 1024       // physical; logical = ceil(N/128) = 782
#define CAP   2048       // slots per bucket (mean 1280, sigma ~36)
#define CHUNK 4096       // edges per bin_fill block
#define TPB   512
#define ASTR  72         // agg16 row stride in ushorts (144 B, 16B-aligned)

typedef unsigned long long u64;
typedef __attribute__((ext_vector_type(8))) short bf16x8;
typedef __attribute__((ext_vector_type(4))) float f32x4;

__device__ inline unsigned short to_bf16(float f) {   // RNE
    unsigned u = __float_as_uint(f);
    u += 0x7FFF + ((u >> 16) & 1);
    return (unsigned short)(u >> 16);
}
__device__ inline float bf_up(unsigned short s) {
    return __uint_as_float(((unsigned)s) << 16);
}

// ---- phase 1: cvt h + pack W + bin edges by dst>>7 into global buckets ----
// Entry: low32 = src | (dstLocal<<24) (dl < 128), high32 = bits(w).
__global__ __launch_bounds__(512) void bin_fill_kernel(
    const float* __restrict__ h, const float* __restrict__ weight,
    const int* __restrict__ e_src, const int* __restrict__ e_dst,
    const float* __restrict__ e_w, int* __restrict__ gcur,
    u64* __restrict__ bucket, ushort* __restrict__ h16,
    ushort* __restrict__ w16, int E, int total4) {
    __shared__ u64 staging[CHUNK];            // 32 KB
    __shared__ unsigned short binOf[CHUNK];   // 8 KB
    __shared__ int hist[NBINS], offs[NBINS], gbase[NBINS], cur[NBINS]; // 16 KB
    __shared__ int part[TPB];                 // 2 KB

    int tid = threadIdx.x;
    int gid = blockIdx.x * TPB + tid;
    int nthreads = gridDim.x * TPB;

    // 0a: h (fp32) -> h16 (bf16), grid-stride over ushort4 groups
    for (int i = gid; i < total4; i += nthreads) {
        float4 v = ((const float4*)h)[i];
        ushort4 o;
        o.x = to_bf16(v.x); o.y = to_bf16(v.y);
        o.z = to_bf16(v.z); o.w = to_bf16(v.w);
        ((ushort4*)h16)[i] = o;
    }
    // 0b: W -> frag-packed bf16: w16[((c*4+s)*64+l)*8+j]
    //     = bf16(W[s*32 + (l>>4)*8 + j][c*16 + (l&15)])
    if (gid < 8192) {
        int j = gid & 7, l = (gid >> 3) & 63, cs = gid >> 9;
        int c = cs >> 2, s = cs & 3, q = l >> 4, m = l & 15;
        w16[gid] = to_bf16(weight[(s * 32 + q * 8 + j) * DFEAT + c * 16 + m]);
    }

    int e0 = blockIdx.x * CHUNK;
    int cc = min(CHUNK, E - e0);

    hist[tid] = 0; hist[tid + 512] = 0;
    __syncthreads();

    int d[8], s[8];
    float w[8];
#pragma unroll
    for (int j = 0; j < 8; ++j) {
        int e = e0 + j * TPB + tid;
        if (e < E) { d[j] = e_dst[e]; s[j] = e_src[e]; w[j] = e_w[e]; }
        else d[j] = -1;
    }
#pragma unroll
    for (int j = 0; j < 8; ++j)
        if (d[j] >= 0) atomicAdd(&hist[d[j] >> 7], 1);
    __syncthreads();

    // exclusive scan of hist[1024]: thread t owns pair (2t, 2t+1)
    int a = hist[2 * tid], b = hist[2 * tid + 1];
    part[tid] = a + b;
    __syncthreads();
    for (int ofs = 1; ofs < TPB; ofs <<= 1) {
        int t = (tid >= ofs) ? part[tid - ofs] : 0;
        __syncthreads();
        part[tid] += t;
        __syncthreads();
    }
    int excl = part[tid] - (a + b);
    offs[2 * tid] = excl;         cur[2 * tid] = excl;
    offs[2 * tid + 1] = excl + a; cur[2 * tid + 1] = excl + a;
    __syncthreads();

    // scatter into bin-sorted LDS staging
#pragma unroll
    for (int j = 0; j < 8; ++j) {
        if (d[j] >= 0) {
            int bb = d[j] >> 7;
            int p = atomicAdd(&cur[bb], 1);
            unsigned lo = (unsigned)s[j] | ((unsigned)(d[j] & 127) << 24);
            staging[p] = ((u64)(unsigned)__float_as_int(w[j]) << 32) | lo;
            binOf[p] = (unsigned short)bb;
        }
    }
    __syncthreads();

    // reserve global space: one atomic per non-empty bin
    for (int t = tid; t < NBINS; t += TPB) {
        int c = hist[t];
        gbase[t] = (c > 0) ? atomicAdd(&gcur[t], c) : 0;
    }
    __syncthreads();

    // flush: bin-contiguous runs -> contiguous global slots
#pragma unroll
    for (int j = 0; j < 8; ++j) {
        int p = j * TPB + tid;
        if (p < cc) {
            int bb = binOf[p];
            bucket[(size_t)bb * CAP + gbase[bb] + (p - offs[bb])] = staging[p];
        }
    }
}

// ---- phase 2: per-bin sort + register-accumulate gather + MFMA epilogue ----
// 512 threads (8 waves), ~37 KB LDS -> 4 blocks/CU. Wave wv gathers nodes
// [wv*16, wv*16+16) and then runs the MFMA epilogue for that same 16-row
// tile (no cross-wave dependency -> no barrier between gather and epilogue).
__global__ __launch_bounds__(512) void spmm_kernel(
    const ushort* __restrict__ h16, const u64* __restrict__ bucket,
    const int* __restrict__ gcur, const ushort* __restrict__ w16,
    const float* __restrict__ ifeat,
    const float* __restrict__ lamda_p, const float* __restrict__ alpha_p,
    const int* __restrict__ layer_p,
    float* __restrict__ out, int N) {
    __shared__ u64 sorted[CAP];                        // 16 KB
    __shared__ __align__(16) ushort agg16[BINSZ * ASTR]; // 18 KB (bf16 agg)
    __shared__ int hist[BINSZ], start[BINSZ], cur[BINSZ], part[BINSZ]; // 2 KB

    int tid = threadIdx.x;
    int bin = blockIdx.x;
    int base = bin << 7;
    int cnt = gcur[bin];
    const u64* bk = bucket + (size_t)bin * CAP;

    if (tid < BINSZ) hist[tid] = 0;
    __syncthreads();

    // histogram by local node id
    for (int p = tid; p < cnt; p += TPB)
        atomicAdd(&hist[(((unsigned)bk[p]) >> 24) & 127], 1);
    __syncthreads();

    // exclusive scan of hist[128]
    int v = 0;
    if (tid < BINSZ) { v = hist[tid]; part[tid] = v; }
    __syncthreads();
    for (int ofs = 1; ofs < BINSZ; ofs <<= 1) {
        int t = (tid < BINSZ && tid >= ofs) ? part[tid - ofs] : 0;
        __syncthreads();
        if (tid < BINSZ) part[tid] += t;
        __syncthreads();
    }
    if (tid < BINSZ) { start[tid] = part[tid] - v; cur[tid] = part[tid] - v; }
    __syncthreads();

    // permute into node-sorted LDS (int LDS atomics: fast, R6-proven)
    for (int p = tid; p < cnt; p += TPB) {
        u64 e = bk[p];
        int pos = atomicAdd(&cur[(((unsigned)e) >> 24) & 127], 1);
        sorted[pos] = e;
    }
    __syncthreads();

    int lane = tid & 63, wv = tid >> 6;
    int g = lane >> 4, m = lane & 15;
    int nn = min(BINSZ, N - base);

    // gather: quad g owns edge t0+s*4+g, lane covers features m*4..m*4+3.
    // wave wv fills agg16 rows [wv*16, wv*16+16).
    for (int k = 0; k < 16; ++k) {
        int nl = wv * 16 + k;
        if (nl >= nn) break;
        int d = hist[nl];
        int b0 = start[nl];
        float a0 = 0.f, a1 = 0.f, a2 = 0.f, a3 = 0.f;
        for (int t0 = 0; t0 < d; t0 += 16) {
#pragma unroll
            for (int s = 0; s < 4; ++s) {
                int idx = t0 + s * 4 + g;
                u64 e = sorted[b0 + min(idx, d - 1)];
                float wt = (idx < d) ? __int_as_float((int)(e >> 32)) : 0.f;
                int src = ((unsigned)e) & 0xFFFFFF;
                ushort4 hv = *(const ushort4*)(h16 + (size_t)src * DFEAT + m * 4);
                a0 += wt * bf_up(hv.x);
                a1 += wt * bf_up(hv.y);
                a2 += wt * bf_up(hv.z);
                a3 += wt * bf_up(hv.w);
            }
        }
        a0 += __shfl_xor(a0, 16); a1 += __shfl_xor(a1, 16);
        a2 += __shfl_xor(a2, 16); a3 += __shfl_xor(a3, 16);
        a0 += __shfl_xor(a0, 32); a1 += __shfl_xor(a1, 32);
        a2 += __shfl_xor(a2, 32); a3 += __shfl_xor(a3, 32);
        if (g == 0) {
            ushort4 o;
            o.x = to_bf16(a0); o.y = to_bf16(a1);
            o.z = to_bf16(a2); o.w = to_bf16(a3);
            *(ushort4*)(agg16 + nl * ASTR + m * 4) = o;
        }
    }

    // fused epilogue for tile rows [wv*16, wv*16+16) -- same-wave data only.
    float alf = alpha_p[0];
    float theta = fminf(1.0f, logf(lamda_p[0] / (float)layer_p[0] + 1.0f));
    int q = lane >> 4;

    // A-frags: agg from LDS (already bf16), i from global (convert)
    bf16x8 faA[2], faI[2];
#pragma unroll
    for (int s = 0; s < 2; ++s)
        faA[s] = *(const bf16x8*)(agg16 + (wv * 16 + m) * ASTR + s * 32 + q * 8);
    {
        const float* ip = ifeat + (size_t)min(base + wv * 16 + m, N - 1) * DFEAT;
#pragma unroll
        for (int s = 0; s < 2; ++s) {
            float4 v0 = *(const float4*)(ip + s * 32 + q * 8);
            float4 v1 = *(const float4*)(ip + s * 32 + q * 8 + 4);
            bf16x8 t;
            t[0] = (short)to_bf16(v0.x); t[1] = (short)to_bf16(v0.y);
            t[2] = (short)to_bf16(v0.z); t[3] = (short)to_bf16(v0.w);
            t[4] = (short)to_bf16(v1.x); t[5] = (short)to_bf16(v1.y);
            t[6] = (short)to_bf16(v1.z); t[7] = (short)to_bf16(v1.w);
            faI[s] = t;
        }
    }

    f32x4 acc[4] = {{0.f, 0.f, 0.f, 0.f}, {0.f, 0.f, 0.f, 0.f},
                    {0.f, 0.f, 0.f, 0.f}, {0.f, 0.f, 0.f, 0.f}};
#pragma unroll
    for (int c = 0; c < 4; ++c) {
#pragma unroll
        for (int s = 0; s < 2; ++s) {
            bf16x8 bA = *(const bf16x8*)(w16 + ((c * 4 + s) * 64 + lane) * 8);
            acc[c] = __builtin_amdgcn_mfma_f32_16x16x32_bf16(faA[s], bA, acc[c], 0, 0, 0);
            bf16x8 bI = *(const bf16x8*)(w16 + ((c * 4 + s + 2) * 64 + lane) * 8);
            acc[c] = __builtin_amdgcn_mfma_f32_16x16x32_bf16(faI[s], bI, acc[c], 0, 0, 0);
        }
    }

    // mix + residual + store (C/D: row = wv*16 + q*4 + r, col = c*16 + m)
#pragma unroll
    for (int c = 0; c < 4; ++c) {
        int col = c * 16 + m;
#pragma unroll
        for (int r = 0; r < 4; ++r) {
            int rowL = wv * 16 + q * 4 + r;
            int row = base + rowL;
            if (row < N) {
                float av = bf_up(agg16[rowL * ASTR + col]);
                float iv = ifeat[(size_t)row * DFEAT + col];
                out[(size_t)row * DFEAT + col] =
                    theta * acc[c][r] +
                    (1.f - theta) * ((1.f - alf) * av + alf * iv) + iv;
            }
        }
    }
}

extern "C" void kernel_launch(void* const* d_in, const int* in_sizes, int n_in,
                              void* d_out, int out_size, void* d_ws, size_t ws_size,
                              hipStream_t stream) {
    const float* h       = (const float*)d_in[0];
    const float* ifeat   = (const float*)d_in[1];
    const float* weight  = (const float*)d_in[2];
    const float* edge_w  = (const float*)d_in[3];
    const float* lamda_p = (const float*)d_in[4];
    const float* alpha_p = (const float*)d_in[5];
    const int*   e_src   = (const int*)d_in[6];
    const int*   e_dst   = (const int*)d_in[7];
    const int*   layer_p = (const int*)d_in[8];
    float* out = (float*)d_out;

    int N = in_sizes[0] / DFEAT;       // 100000
    int E = in_sizes[3];               // 1000000
    int nbins = (N + BINSZ - 1) >> 7;  // 782

    // ws: gcur[1024] (4KB) | bucket 16.78MB | h16 12.8MB | w16 16KB
    int* gcur = (int*)d_ws;
    u64* bucket = (u64*)((char*)d_ws + 4096);
    ushort* h16 = (ushort*)((char*)bucket + (size_t)NBINS * CAP * sizeof(u64));
    ushort* w16 = h16 + (size_t)N * DFEAT;

    hipMemsetAsync(gcur, 0, NBINS * sizeof(int), stream);

    int total4 = N * DFEAT / 4;
    bin_fill_kernel<<<(E + CHUNK - 1) / CHUNK, TPB, 0, stream>>>(
        h, weight, e_src, e_dst, edge_w, gcur, bucket, h16, w16, E, total4);

    spmm_kernel<<<nbins, TPB, 0, stream>>>(
        h16, bucket, gcur, w16, ifeat, lamda_p, alpha_p, layer_p, out, N);
}